// Round 15
// baseline (139.714 us; speedup 1.0000x reference)
//
#include <hip/hip_runtime.h>
#include <math.h>

#define NN 8192
#define FIN 512
#define HD 128
#define CAP 128

typedef float f32x4 __attribute__((ext_vector_type(4)));

// ---------------------------------------------------------------------------
// K0: dense GEMMs + weight fold (R9/R11 config: 32-row tiles, 513 blocks).
//   blocks 0-255:   xl  = x @ Wl1
//   blocks 256-511: xrb = x @ Wr1 + b1   (bias folded into epilogue)
//   block 512:      wsm = {Wl2@Wd, Wr2@Wd, b2@Wd+bd}
// ---------------------------------------------------------------------------
__global__ __launch_bounds__(256) void k_gemm(
    const float* __restrict__ x, const float* __restrict__ Wl1,
    const float* __restrict__ Wr1, const float* __restrict__ b1,
    const float* __restrict__ Wl2, const float* __restrict__ Wr2,
    const float* __restrict__ b2, const float* __restrict__ Wd,
    const float* __restrict__ bd,
    float* __restrict__ xl, float* __restrict__ xr,
    float4* __restrict__ wsm)
{
    __shared__ float As[32][32];
    __shared__ float Bs[32][128];
    const int tid = threadIdx.x;
    const int b = blockIdx.x;

    if (b == 512) {
        const int t = tid;
        if (t < HD) {
            float l0 = 0, l1 = 0, l2 = 0, r0 = 0, r1 = 0, r2 = 0;
            for (int c = 0; c < HD; ++c) {
                const float w0 = Wd[c * 3 + 0], w1 = Wd[c * 3 + 1], w2 = Wd[c * 3 + 2];
                const float wl = Wl2[t * HD + c];
                const float wr = Wr2[t * HD + c];
                l0 = fmaf(wl, w0, l0); l1 = fmaf(wl, w1, l1); l2 = fmaf(wl, w2, l2);
                r0 = fmaf(wr, w0, r0); r1 = fmaf(wr, w1, r1); r2 = fmaf(wr, w2, r2);
            }
            wsm[t]       = make_float4(l0, l1, l2, 0.f);
            wsm[128 + t] = make_float4(r0, r1, r2, 0.f);
            if (t == 0) {
                float c0 = bd[0], c1 = bd[1], c2 = bd[2];
                for (int c = 0; c < HD; ++c) {
                    c0 = fmaf(b2[c], Wd[c * 3 + 0], c0);
                    c1 = fmaf(b2[c], Wd[c * 3 + 1], c1);
                    c2 = fmaf(b2[c], Wd[c * 3 + 2], c2);
                }
                wsm[256] = make_float4(c0, c1, c2, 0.f);
            }
        }
        return;
    }

    const bool left = (b < 256);
    const float* W = left ? Wl1 : Wr1;
    float* Cout    = left ? xl  : xr;
    const int row0 = (b & 255) * 32;
    const int rg = tid >> 5, cg = tid & 31;
    const int ar = tid >> 3, ak = (tid & 7) * 4;
    const int bk = tid >> 5, bc = (tid & 31) * 4;
    float acc[4][4] = {};
    for (int ch = 0; ch < FIN / 32; ++ch) {
        const int kc = ch * 32;
        __syncthreads();
        const float4 va = *(const float4*)(x + (size_t)(row0 + ar) * FIN + kc + ak);
        As[ak + 0][ar] = va.x; As[ak + 1][ar] = va.y;
        As[ak + 2][ar] = va.z; As[ak + 3][ar] = va.w;
        #pragma unroll
        for (int it = 0; it < 4; ++it)
            *(float4*)&Bs[bk + 8 * it][bc] =
                *(const float4*)(W + (size_t)(kc + bk + 8 * it) * HD + bc);
        __syncthreads();
        #pragma unroll
        for (int k = 0; k < 32; ++k) {
            const float4 a4 = *(const float4*)&As[k][rg * 4];
            const float4 b4 = *(const float4*)&Bs[k][cg * 4];
            const float av[4] = {a4.x, a4.y, a4.z, a4.w};
            const float bv[4] = {b4.x, b4.y, b4.z, b4.w};
            #pragma unroll
            for (int a = 0; a < 4; ++a)
                #pragma unroll
                for (int bb = 0; bb < 4; ++bb)
                    acc[a][bb] = fmaf(av[a], bv[bb], acc[a][bb]);
        }
    }
    float4 bias = make_float4(0.f, 0.f, 0.f, 0.f);
    if (!left) bias = ((const float4*)b1)[cg];   // fold b1 into xr
    #pragma unroll
    for (int a = 0; a < 4; ++a)
        *(float4*)(Cout + (size_t)(row0 + rg * 4 + a) * HD + cg * 4) =
            make_float4(acc[a][0] + bias.x, acc[a][1] + bias.y,
                        acc[a][2] + bias.z, acc[a][3] + bias.w);
}

// ---------------------------------------------------------------------------
// K1: scan with INTERLEAVED gather (R11) + 2-deep load pipelining: both 1KB
// row loads of an iteration-pair are issued before any ballot processing,
// doubling bytes-in-flight per wave (2KB).
// ---------------------------------------------------------------------------
__global__ __launch_bounds__(256) void k_scanagg(
    const float* __restrict__ adj, const float* __restrict__ xl,
    const float* __restrict__ xrb, const float4* __restrict__ wsm,
    int* __restrict__ nbr, int* __restrict__ degi, float* __restrict__ degf,
    float4* __restrict__ u4, float4* __restrict__ v4)
{
    __shared__ int lists[4][CAP];
    const int w = threadIdx.x >> 6, lane = threadIdx.x & 63;
    const int i = blockIdx.x * 4 + w;
    int* lst = lists[w];

    const f32x4* row = (const f32x4*)(adj + (size_t)i * NN);
    const unsigned long long lmask = (1ull << lane) - 1ull;
    int cnt = 0;
    float s0 = 0.f, s1 = 0.f;                   // cols 2*lane, 2*lane+1
    for (int it = 0; it < NN / 256; it += 2) {  // 16 pairs, 2KB/wave in flight
        const f32x4 a0 = __builtin_nontemporal_load(&row[it * 64 + lane]);
        const f32x4 a1 = __builtin_nontemporal_load(&row[(it + 1) * 64 + lane]);
        #pragma unroll
        for (int p = 0; p < 2; ++p) {
            const f32x4 a = p ? a1 : a0;
            const int itp = it + p;
            const float vals[4] = {a.x, a.y, a.z, a.w};
            #pragma unroll
            for (int e = 0; e < 4; ++e) {
                const bool nz = (vals[e] != 0.0f);
                const unsigned long long m = __ballot(nz);
                if (nz) {
                    const int pp = cnt + (int)__popcll(m & lmask);
                    if (pp < CAP) lst[pp] = (itp * 64 + lane) * 4 + e;
                }
                cnt += (int)__popcll(m);
                // interleaved gather: m wave-uniform; loads hide under scan
                unsigned long long mm = m;
                while (mm) {
                    const int bit = (int)__builtin_ctzll(mm);
                    mm &= mm - 1;
                    const int j = (itp * 64 + bit) * 4 + e;
                    const float2 g = ((const float2*)(xl + (size_t)j * HD))[lane];
                    s0 += g.x; s1 += g.y;
                }
            }
        }
    }
    const int d = cnt < CAP ? cnt : CAP;
    const float inv = 1.0f / fmaxf((float)cnt, 1.0f);
    // export for K2 (wave-local LDS -> lgkmcnt ordering suffices)
    if (lane < d)      nbr[(size_t)i * CAP + lane]      = lst[lane];
    if (lane + 64 < d) nbr[(size_t)i * CAP + lane + 64] = lst[lane + 64];
    if (lane == 0) { degi[i] = d; degf[i] = fmaxf((float)cnt, 1.0f); }

    // ---- epilogue: h + projection (pure register math) ----
    const float2 rr = ((const float2*)(xrb + (size_t)i * HD))[lane];  // has +b1
    const float h0 = fmaxf(fmaf(s0, inv, rr.x), 0.f);
    const float h1 = fmaxf(fmaf(s1, inv, rr.y), 0.f);
    const float4 w0 = wsm[2 * lane], w1 = wsm[2 * lane + 1];
    const float4 q0 = wsm[128 + 2 * lane], q1 = wsm[128 + 2 * lane + 1];
    float u0 = h0 * w0.x + h1 * w1.x;
    float u1 = h0 * w0.y + h1 * w1.y;
    float u2 = h0 * w0.z + h1 * w1.z;
    float v0 = h0 * q0.x + h1 * q1.x;
    float v1 = h0 * q0.y + h1 * q1.y;
    float v2 = h0 * q0.z + h1 * q1.z;
    #pragma unroll
    for (int off = 32; off; off >>= 1) {
        u0 += __shfl_xor(u0, off); u1 += __shfl_xor(u1, off); u2 += __shfl_xor(u2, off);
        v0 += __shfl_xor(v0, off); v1 += __shfl_xor(v1, off); v2 += __shfl_xor(v2, off);
    }
    if (lane == 0) {
        u4[i] = make_float4(u0, u1, u2, 0.f);
        v4[i] = make_float4(v0, v1, v2, 0.f);
    }
}

// ---------------------------------------------------------------------------
// K2: y[i] = mean_j u[j] + v[i] + c   (3-wide second-hop aggregation)
// ---------------------------------------------------------------------------
__global__ __launch_bounds__(256) void k_ycomb(
    const float4* __restrict__ u4, const float4* __restrict__ v4,
    const int* __restrict__ nbr, const int* __restrict__ degi,
    const float* __restrict__ degf, const float4* __restrict__ wsm,
    float4* __restrict__ y4)
{
    const int hw = threadIdx.x >> 5;
    const int lane = threadIdx.x & 31;
    const int i = blockIdx.x * 8 + hw;
    const int d = degi[i];
    const float inv = 1.0f / degf[i];
    const int* lst = nbr + (size_t)i * CAP;
    float s0 = 0.f, s1 = 0.f, s2 = 0.f;
    for (int base = 0; base + lane < d; base += 32) {
        const float4 u = u4[lst[base + lane]];
        s0 += u.x; s1 += u.y; s2 += u.z;
    }
    #pragma unroll
    for (int off = 16; off; off >>= 1) {
        s0 += __shfl_xor(s0, off); s1 += __shfl_xor(s1, off); s2 += __shfl_xor(s2, off);
    }
    if (lane == 0) {
        const float4 v = v4[i];
        const float4 c = wsm[256];
        y4[i] = make_float4(fmaf(s0, inv, v.x + c.x),
                            fmaf(s1, inv, v.y + c.y),
                            fmaf(s2, inv, v.z + c.z), 0.f);
    }
}

// ---------------------------------------------------------------------------
// K3: out[i,j] = ||y_i - y_j||, tiled 32 i x 1024 j per block.
// Raw v_sqrt_f32 (~1 ulp; abs threshold 0.226) to cut VALU near the
// write-BW/VALU crossover. Non-temporal float4 stores.
// ---------------------------------------------------------------------------
__global__ __launch_bounds__(256) void k_cdist(
    const float4* __restrict__ y4, float* __restrict__ out)
{
    __shared__ float4 yis[32];
    const int t = threadIdx.x;
    const int i0 = blockIdx.y * 32;
    if (t < 32) yis[t] = y4[i0 + t];
    __syncthreads();
    const int j0 = blockIdx.x * 1024 + t * 4;
    const float4 a0 = y4[j0 + 0], a1 = y4[j0 + 1];
    const float4 a2 = y4[j0 + 2], a3 = y4[j0 + 3];
    float* op = out + (size_t)i0 * NN + j0;
    #pragma unroll 4
    for (int ii = 0; ii < 32; ++ii) {
        const float4 yi = yis[ii];
        f32x4 r;
        { const float dx = yi.x - a0.x, dy = yi.y - a0.y, dz = yi.z - a0.z;
          r.x = __builtin_amdgcn_sqrtf(fmaf(dx, dx, fmaf(dy, dy, dz * dz))); }
        { const float dx = yi.x - a1.x, dy = yi.y - a1.y, dz = yi.z - a1.z;
          r.y = __builtin_amdgcn_sqrtf(fmaf(dx, dx, fmaf(dy, dy, dz * dz))); }
        { const float dx = yi.x - a2.x, dy = yi.y - a2.y, dz = yi.z - a2.z;
          r.z = __builtin_amdgcn_sqrtf(fmaf(dx, dx, fmaf(dy, dy, dz * dz))); }
        { const float dx = yi.x - a3.x, dy = yi.y - a3.y, dz = yi.z - a3.z;
          r.w = __builtin_amdgcn_sqrtf(fmaf(dx, dx, fmaf(dy, dy, dz * dz))); }
        __builtin_nontemporal_store(r, (f32x4*)op);
        op += NN;
    }
}

// ---------------------------------------------------------------------------
extern "C" void kernel_launch(void* const* d_in, const int* in_sizes, int n_in,
                              void* d_out, int out_size, void* d_ws, size_t ws_size,
                              hipStream_t stream) {
    const float* x   = (const float*)d_in[0];
    const float* adj = (const float*)d_in[1];
    const float* Wl1 = (const float*)d_in[2];
    const float* Wr1 = (const float*)d_in[3];
    const float* b1  = (const float*)d_in[4];
    const float* Wl2 = (const float*)d_in[5];
    const float* Wr2 = (const float*)d_in[6];
    const float* b2  = (const float*)d_in[7];
    const float* Wd  = (const float*)d_in[8];
    const float* bd  = (const float*)d_in[9];
    float* out = (float*)d_out;

    // ---- workspace layout (16B-aligned slots) ----
    char* ws = (char*)d_ws;
    const size_t nbr_b  = (size_t)NN * CAP * 4;    // 4 MB
    const size_t deg_b  = (size_t)NN * 4;          // 32 KB each
    const size_t vec_b  = (size_t)NN * 16;         // 128 KB each (u4,v4,y4)
    const size_t wsm_b  = 272 * 16;
    const size_t small_total = nbr_b + 2 * deg_b + 3 * vec_b + wsm_b;
    const size_t xl_b = (size_t)NN * HD * 4;       // 4 MB each

    size_t off = 0;
    int*    nbr  = (int*)(ws + off);    off += nbr_b;
    int*    degi = (int*)(ws + off);    off += deg_b;
    float*  degf = (float*)(ws + off);  off += deg_b;
    float4* u4   = (float4*)(ws + off); off += vec_b;
    float4* v4   = (float4*)(ws + off); off += vec_b;
    float4* y4   = (float4*)(ws + off); off += vec_b;
    float4* wsm  = (float4*)(ws + off); off += wsm_b;

    // xl/xrb: in ws if it fits, else carve from d_out (dead before k_cdist).
    char* big = (ws_size >= small_total + 2 * xl_b) ? (ws + off) : (char*)d_out;
    float* xl  = (float*)(big);
    float* xrb = (float*)(big + xl_b);

    // ---- pipeline ----
    k_gemm<<<513, 256, 0, stream>>>(x, Wl1, Wr1, b1, Wl2, Wr2, b2, Wd, bd,
                                    xl, xrb, wsm);

    k_scanagg<<<NN / 4, 256, 0, stream>>>(adj, xl, xrb, wsm,
                                          nbr, degi, degf, u4, v4);

    k_ycomb<<<NN / 8, 256, 0, stream>>>(u4, v4, nbr, degi, degf, wsm, y4);

    k_cdist<<<dim3(NN / 1024, NN / 32), 256, 0, stream>>>(y4, out);
}

// Round 16
// 138.970 us; speedup vs baseline: 1.0054x; 1.0054x over previous
//
#include <hip/hip_runtime.h>
#include <math.h>

#define NN 8192
#define FIN 512
#define HD 128
#define CAP 128

typedef float f32x4 __attribute__((ext_vector_type(4)));

// ---------------------------------------------------------------------------
// K0: dense GEMMs + weight fold (R9/R11 config: 32-row tiles, 513 blocks).
//   blocks 0-255:   xl  = x @ Wl1
//   blocks 256-511: xrb = x @ Wr1 + b1   (bias folded into epilogue)
//   block 512:      wsm = {Wl2@Wd, Wr2@Wd, b2@Wd+bd}
// ---------------------------------------------------------------------------
__global__ __launch_bounds__(256) void k_gemm(
    const float* __restrict__ x, const float* __restrict__ Wl1,
    const float* __restrict__ Wr1, const float* __restrict__ b1,
    const float* __restrict__ Wl2, const float* __restrict__ Wr2,
    const float* __restrict__ b2, const float* __restrict__ Wd,
    const float* __restrict__ bd,
    float* __restrict__ xl, float* __restrict__ xr,
    float4* __restrict__ wsm)
{
    __shared__ float As[32][32];
    __shared__ float Bs[32][128];
    const int tid = threadIdx.x;
    const int b = blockIdx.x;

    if (b == 512) {
        const int t = tid;
        if (t < HD) {
            float l0 = 0, l1 = 0, l2 = 0, r0 = 0, r1 = 0, r2 = 0;
            for (int c = 0; c < HD; ++c) {
                const float w0 = Wd[c * 3 + 0], w1 = Wd[c * 3 + 1], w2 = Wd[c * 3 + 2];
                const float wl = Wl2[t * HD + c];
                const float wr = Wr2[t * HD + c];
                l0 = fmaf(wl, w0, l0); l1 = fmaf(wl, w1, l1); l2 = fmaf(wl, w2, l2);
                r0 = fmaf(wr, w0, r0); r1 = fmaf(wr, w1, r1); r2 = fmaf(wr, w2, r2);
            }
            wsm[t]       = make_float4(l0, l1, l2, 0.f);
            wsm[128 + t] = make_float4(r0, r1, r2, 0.f);
            if (t == 0) {
                float c0 = bd[0], c1 = bd[1], c2 = bd[2];
                for (int c = 0; c < HD; ++c) {
                    c0 = fmaf(b2[c], Wd[c * 3 + 0], c0);
                    c1 = fmaf(b2[c], Wd[c * 3 + 1], c1);
                    c2 = fmaf(b2[c], Wd[c * 3 + 2], c2);
                }
                wsm[256] = make_float4(c0, c1, c2, 0.f);
            }
        }
        return;
    }

    const bool left = (b < 256);
    const float* W = left ? Wl1 : Wr1;
    float* Cout    = left ? xl  : xr;
    const int row0 = (b & 255) * 32;
    const int rg = tid >> 5, cg = tid & 31;
    const int ar = tid >> 3, ak = (tid & 7) * 4;
    const int bk = tid >> 5, bc = (tid & 31) * 4;
    float acc[4][4] = {};
    for (int ch = 0; ch < FIN / 32; ++ch) {
        const int kc = ch * 32;
        __syncthreads();
        const float4 va = *(const float4*)(x + (size_t)(row0 + ar) * FIN + kc + ak);
        As[ak + 0][ar] = va.x; As[ak + 1][ar] = va.y;
        As[ak + 2][ar] = va.z; As[ak + 3][ar] = va.w;
        #pragma unroll
        for (int it = 0; it < 4; ++it)
            *(float4*)&Bs[bk + 8 * it][bc] =
                *(const float4*)(W + (size_t)(kc + bk + 8 * it) * HD + bc);
        __syncthreads();
        #pragma unroll
        for (int k = 0; k < 32; ++k) {
            const float4 a4 = *(const float4*)&As[k][rg * 4];
            const float4 b4 = *(const float4*)&Bs[k][cg * 4];
            const float av[4] = {a4.x, a4.y, a4.z, a4.w};
            const float bv[4] = {b4.x, b4.y, b4.z, b4.w};
            #pragma unroll
            for (int a = 0; a < 4; ++a)
                #pragma unroll
                for (int bb = 0; bb < 4; ++bb)
                    acc[a][bb] = fmaf(av[a], bv[bb], acc[a][bb]);
        }
    }
    float4 bias = make_float4(0.f, 0.f, 0.f, 0.f);
    if (!left) bias = ((const float4*)b1)[cg];   // fold b1 into xr
    #pragma unroll
    for (int a = 0; a < 4; ++a)
        *(float4*)(Cout + (size_t)(row0 + rg * 4 + a) * HD + cg * 4) =
            make_float4(acc[a][0] + bias.x, acc[a][1] + bias.y,
                        acc[a][2] + bias.z, acc[a][3] + bias.w);
}

// ---------------------------------------------------------------------------
// K1: scan with INTERLEAVED gather (R11) + 2-deep load pipelining: both 1KB
// row loads of an iteration-pair are issued before any ballot processing,
// doubling bytes-in-flight per wave (2KB).
// ---------------------------------------------------------------------------
__global__ __launch_bounds__(256) void k_scanagg(
    const float* __restrict__ adj, const float* __restrict__ xl,
    const float* __restrict__ xrb, const float4* __restrict__ wsm,
    int* __restrict__ nbr, int* __restrict__ degi, float* __restrict__ degf,
    float4* __restrict__ u4, float4* __restrict__ v4)
{
    __shared__ int lists[4][CAP];
    const int w = threadIdx.x >> 6, lane = threadIdx.x & 63;
    const int i = blockIdx.x * 4 + w;
    int* lst = lists[w];

    const f32x4* row = (const f32x4*)(adj + (size_t)i * NN);
    const unsigned long long lmask = (1ull << lane) - 1ull;
    int cnt = 0;
    float s0 = 0.f, s1 = 0.f;                   // cols 2*lane, 2*lane+1
    for (int it = 0; it < NN / 256; it += 2) {  // 16 pairs, 2KB/wave in flight
        const f32x4 a0 = __builtin_nontemporal_load(&row[it * 64 + lane]);
        const f32x4 a1 = __builtin_nontemporal_load(&row[(it + 1) * 64 + lane]);
        #pragma unroll
        for (int p = 0; p < 2; ++p) {
            const f32x4 a = p ? a1 : a0;
            const int itp = it + p;
            const float vals[4] = {a.x, a.y, a.z, a.w};
            #pragma unroll
            for (int e = 0; e < 4; ++e) {
                const bool nz = (vals[e] != 0.0f);
                const unsigned long long m = __ballot(nz);
                if (nz) {
                    const int pp = cnt + (int)__popcll(m & lmask);
                    if (pp < CAP) lst[pp] = (itp * 64 + lane) * 4 + e;
                }
                cnt += (int)__popcll(m);
                // interleaved gather: m wave-uniform; loads hide under scan
                unsigned long long mm = m;
                while (mm) {
                    const int bit = (int)__builtin_ctzll(mm);
                    mm &= mm - 1;
                    const int j = (itp * 64 + bit) * 4 + e;
                    const float2 g = ((const float2*)(xl + (size_t)j * HD))[lane];
                    s0 += g.x; s1 += g.y;
                }
            }
        }
    }
    const int d = cnt < CAP ? cnt : CAP;
    const float inv = 1.0f / fmaxf((float)cnt, 1.0f);
    // export for K2 (wave-local LDS -> lgkmcnt ordering suffices)
    if (lane < d)      nbr[(size_t)i * CAP + lane]      = lst[lane];
    if (lane + 64 < d) nbr[(size_t)i * CAP + lane + 64] = lst[lane + 64];
    if (lane == 0) { degi[i] = d; degf[i] = fmaxf((float)cnt, 1.0f); }

    // ---- epilogue: h + projection (pure register math) ----
    const float2 rr = ((const float2*)(xrb + (size_t)i * HD))[lane];  // has +b1
    const float h0 = fmaxf(fmaf(s0, inv, rr.x), 0.f);
    const float h1 = fmaxf(fmaf(s1, inv, rr.y), 0.f);
    const float4 w0 = wsm[2 * lane], w1 = wsm[2 * lane + 1];
    const float4 q0 = wsm[128 + 2 * lane], q1 = wsm[128 + 2 * lane + 1];
    float u0 = h0 * w0.x + h1 * w1.x;
    float u1 = h0 * w0.y + h1 * w1.y;
    float u2 = h0 * w0.z + h1 * w1.z;
    float v0 = h0 * q0.x + h1 * q1.x;
    float v1 = h0 * q0.y + h1 * q1.y;
    float v2 = h0 * q0.z + h1 * q1.z;
    #pragma unroll
    for (int off = 32; off; off >>= 1) {
        u0 += __shfl_xor(u0, off); u1 += __shfl_xor(u1, off); u2 += __shfl_xor(u2, off);
        v0 += __shfl_xor(v0, off); v1 += __shfl_xor(v1, off); v2 += __shfl_xor(v2, off);
    }
    if (lane == 0) {
        u4[i] = make_float4(u0, u1, u2, 0.f);
        v4[i] = make_float4(v0, v1, v2, 0.f);
    }
}

// ---------------------------------------------------------------------------
// K2: y[i] = mean_j u[j] + v[i] + c   (3-wide second-hop aggregation)
// ---------------------------------------------------------------------------
__global__ __launch_bounds__(256) void k_ycomb(
    const float4* __restrict__ u4, const float4* __restrict__ v4,
    const int* __restrict__ nbr, const int* __restrict__ degi,
    const float* __restrict__ degf, const float4* __restrict__ wsm,
    float4* __restrict__ y4)
{
    const int hw = threadIdx.x >> 5;
    const int lane = threadIdx.x & 31;
    const int i = blockIdx.x * 8 + hw;
    const int d = degi[i];
    const float inv = 1.0f / degf[i];
    const int* lst = nbr + (size_t)i * CAP;
    float s0 = 0.f, s1 = 0.f, s2 = 0.f;
    for (int base = 0; base + lane < d; base += 32) {
        const float4 u = u4[lst[base + lane]];
        s0 += u.x; s1 += u.y; s2 += u.z;
    }
    #pragma unroll
    for (int off = 16; off; off >>= 1) {
        s0 += __shfl_xor(s0, off); s1 += __shfl_xor(s1, off); s2 += __shfl_xor(s2, off);
    }
    if (lane == 0) {
        const float4 v = v4[i];
        const float4 c = wsm[256];
        y4[i] = make_float4(fmaf(s0, inv, v.x + c.x),
                            fmaf(s1, inv, v.y + c.y),
                            fmaf(s2, inv, v.z + c.z), 0.f);
    }
}

// ---------------------------------------------------------------------------
// K3: out[i,j] = ||y_i - y_j||, tiled 32 i x 1024 j per block.
// Raw v_sqrt_f32 (~1 ulp; abs threshold 0.226) to cut VALU near the
// write-BW/VALU crossover. Non-temporal float4 stores.
// ---------------------------------------------------------------------------
__global__ __launch_bounds__(256) void k_cdist(
    const float4* __restrict__ y4, float* __restrict__ out)
{
    __shared__ float4 yis[32];
    const int t = threadIdx.x;
    const int i0 = blockIdx.y * 32;
    if (t < 32) yis[t] = y4[i0 + t];
    __syncthreads();
    const int j0 = blockIdx.x * 1024 + t * 4;
    const float4 a0 = y4[j0 + 0], a1 = y4[j0 + 1];
    const float4 a2 = y4[j0 + 2], a3 = y4[j0 + 3];
    float* op = out + (size_t)i0 * NN + j0;
    #pragma unroll 4
    for (int ii = 0; ii < 32; ++ii) {
        const float4 yi = yis[ii];
        f32x4 r;
        { const float dx = yi.x - a0.x, dy = yi.y - a0.y, dz = yi.z - a0.z;
          r.x = __builtin_amdgcn_sqrtf(fmaf(dx, dx, fmaf(dy, dy, dz * dz))); }
        { const float dx = yi.x - a1.x, dy = yi.y - a1.y, dz = yi.z - a1.z;
          r.y = __builtin_amdgcn_sqrtf(fmaf(dx, dx, fmaf(dy, dy, dz * dz))); }
        { const float dx = yi.x - a2.x, dy = yi.y - a2.y, dz = yi.z - a2.z;
          r.z = __builtin_amdgcn_sqrtf(fmaf(dx, dx, fmaf(dy, dy, dz * dz))); }
        { const float dx = yi.x - a3.x, dy = yi.y - a3.y, dz = yi.z - a3.z;
          r.w = __builtin_amdgcn_sqrtf(fmaf(dx, dx, fmaf(dy, dy, dz * dz))); }
        __builtin_nontemporal_store(r, (f32x4*)op);
        op += NN;
    }
}

// ---------------------------------------------------------------------------
extern "C" void kernel_launch(void* const* d_in, const int* in_sizes, int n_in,
                              void* d_out, int out_size, void* d_ws, size_t ws_size,
                              hipStream_t stream) {
    const float* x   = (const float*)d_in[0];
    const float* adj = (const float*)d_in[1];
    const float* Wl1 = (const float*)d_in[2];
    const float* Wr1 = (const float*)d_in[3];
    const float* b1  = (const float*)d_in[4];
    const float* Wl2 = (const float*)d_in[5];
    const float* Wr2 = (const float*)d_in[6];
    const float* b2  = (const float*)d_in[7];
    const float* Wd  = (const float*)d_in[8];
    const float* bd  = (const float*)d_in[9];
    float* out = (float*)d_out;

    // ---- workspace layout (16B-aligned slots) ----
    char* ws = (char*)d_ws;
    const size_t nbr_b  = (size_t)NN * CAP * 4;    // 4 MB
    const size_t deg_b  = (size_t)NN * 4;          // 32 KB each
    const size_t vec_b  = (size_t)NN * 16;         // 128 KB each (u4,v4,y4)
    const size_t wsm_b  = 272 * 16;
    const size_t small_total = nbr_b + 2 * deg_b + 3 * vec_b + wsm_b;
    const size_t xl_b = (size_t)NN * HD * 4;       // 4 MB each

    size_t off = 0;
    int*    nbr  = (int*)(ws + off);    off += nbr_b;
    int*    degi = (int*)(ws + off);    off += deg_b;
    float*  degf = (float*)(ws + off);  off += deg_b;
    float4* u4   = (float4*)(ws + off); off += vec_b;
    float4* v4   = (float4*)(ws + off); off += vec_b;
    float4* y4   = (float4*)(ws + off); off += vec_b;
    float4* wsm  = (float4*)(ws + off); off += wsm_b;

    // xl/xrb: in ws if it fits, else carve from d_out (dead before k_cdist).
    char* big = (ws_size >= small_total + 2 * xl_b) ? (ws + off) : (char*)d_out;
    float* xl  = (float*)(big);
    float* xrb = (float*)(big + xl_b);

    // ---- pipeline ----
    k_gemm<<<513, 256, 0, stream>>>(x, Wl1, Wr1, b1, Wl2, Wr2, b2, Wd, bd,
                                    xl, xrb, wsm);

    k_scanagg<<<NN / 4, 256, 0, stream>>>(adj, xl, xrb, wsm,
                                          nbr, degi, degf, u4, v4);

    k_ycomb<<<NN / 8, 256, 0, stream>>>(u4, v4, nbr, degi, degf, wsm, y4);

    k_cdist<<<dim3(NN / 1024, NN / 32), 256, 0, stream>>>(y4, out);
}